// Round 9
// baseline (53.805 us; speedup 1.0000x reference)
//
#include <hip/hip_runtime.h>
#include <hip/hip_bf16.h>

// Shapes: keypoints (8,5,2) f32, mesh_grid (1024,2) f32, W (10,512) f32,
// distance_matrix (1024,1024) i32 in [0,64). Output (8,8,1024,1024) f32.
//
// Reshape semantics: A (B,N,512) -> (B,8,N,64) row-major raw reshape:
//   n_orig = h*128 + (n_new>>3);  o = (n_new&7)*64 + k
// out[b,h,n,m] = A_new[b,h,n, dm[n,m]]
//
// R9 = final matrix cell {nt stores, XCD-slab mapping}. x = bid&7 pins each
// XCD to planes 8x..8x+7, j-sequential n-fast within slab -> each XCD emits
// ~8 long contiguous nt write streams. vs R5 ({nt, n-fast}, 47.6us): mapping
// only. vs R8 ({plain, slab}, 53.3us): store mode only. One wave = one 4 KB
// row; one-register table (k = lane); ds_bpermute gather (conflict-free).

#define NN 1024

typedef float f32x4 __attribute__((ext_vector_type(4)));

__global__ __launch_bounds__(256) void KR_RPE_10582799417497_kernel(
    const float* __restrict__ kp,    // (8,5,2)
    const float* __restrict__ mesh,  // (1024,2)
    const float* __restrict__ W,     // (10,512)
    const int*   __restrict__ dm,    // (1024,1024)
    float* __restrict__ out)         // (8,8,1024,1024)
{
    const int bid  = blockIdx.x;
    const int x    = bid & 7;         // XCD id (dispatch round-robin)
    const int j    = bid >> 3;        // 0..2047 sequential per XCD
    const int g    = j >> 10;         // plane-group within slab: 0..1
    const int n    = j & (NN - 1);    // row (fast)
    const int t    = threadIdx.x;
    const int lane = t & 63;
    const int w    = t >> 6;          // wave 0..3
    const int bh   = x * 8 + g * 4 + w;  // this wave's output plane
    const int b    = bh >> 3, h = bh & 7;

    const int n0 = n >> 3;            // n_orig = h*128 + n0
    const int oo = (n & 7) * 64;      // o base
    const int k  = lane;              // this lane's table column

    // W column slice for k (coalesced 256 B per load)
    float Wv[10];
#pragma unroll
    for (int f = 0; f < 10; ++f) Wv[f] = W[f * 512 + oo + k];

    // one-register gather table: A[bh][k = lane]
    const int n_orig = h * 128 + n0;
    const float mx = mesh[n_orig * 2 + 0];
    const float my = mesh[n_orig * 2 + 1];
    float acc = 0.f;
#pragma unroll
    for (int p = 0; p < 5; ++p) {
        acc += (mx - kp[b * 10 + p * 2 + 0]) * Wv[p * 2 + 0]
             + (my - kp[b * 10 + p * 2 + 1]) * Wv[p * 2 + 1];
    }
    const int s = __float_as_int(acc);

    const int* dr = dm + (size_t)n * NN;
    float* op = out + ((size_t)bh * NN + n) * NN;   // this wave's 4 KB row

#pragma unroll
    for (int it = 0; it < 4; ++it) {
        const int4 kk = *(const int4*)(dr + it * 256 + lane * 4);
        f32x4 v;
        v.x = __int_as_float(__builtin_amdgcn_ds_bpermute(kk.x * 4, s));
        v.y = __int_as_float(__builtin_amdgcn_ds_bpermute(kk.y * 4, s));
        v.z = __int_as_float(__builtin_amdgcn_ds_bpermute(kk.z * 4, s));
        v.w = __int_as_float(__builtin_amdgcn_ds_bpermute(kk.w * 4, s));
        __builtin_nontemporal_store(v, (f32x4*)(op + it * 256 + lane * 4));
    }
}

extern "C" void kernel_launch(void* const* d_in, const int* in_sizes, int n_in,
                              void* d_out, int out_size, void* d_ws, size_t ws_size,
                              hipStream_t stream) {
    const float* kp   = (const float*)d_in[0];
    const float* mesh = (const float*)d_in[1];
    const float* W    = (const float*)d_in[2];
    const int*   dm   = (const int*)d_in[3];
    float* out = (float*)d_out;

    KR_RPE_10582799417497_kernel<<<16 * NN, 256, 0, stream>>>(kp, mesh, W, dm, out);
}

// Round 10
// 47.324 us; speedup vs baseline: 1.1369x; 1.1369x over previous
//
#include <hip/hip_runtime.h>
#include <hip/hip_bf16.h>

// Shapes: keypoints (8,5,2) f32, mesh_grid (1024,2) f32, W (10,512) f32,
// distance_matrix (1024,1024) i32 in [0,64). Output (8,8,1024,1024) f32.
//
// Reshape semantics: A (B,N,512) -> (B,8,N,64) row-major raw reshape:
//   n_orig = h*128 + (n_new>>3);  o = (n_new&7)*64 + k
// out[b,h,n,m] = A_new[b,h,n, dm[n,m]]
//
// FINAL (= R5, best of the {store-mode} x {mapping} matrix):
//   {nt, n-fast} 47.6us | {plain, n-fast} 51.6 | {nt, 4-row} 53.1
//   | {plain, slab} 53.3 | {nt, slab} 53.8
// One WAVE = one contiguous 4 KB output row (plane bh = g*4+w, row n).
// Gather table A[bh][k] lives one-element-per-lane in ONE register (k=lane);
// gather via ds_bpermute (crossbar, conflict-free, immune to duplicate
// indices); 4 x 1 KB float4 nontemporal stores (nt: full-line overwrite,
// L2 bypass worth ~4us). blockIdx n-fast: co-resident blocks write
// consecutive rows of the same 4 planes. 5.7 TB/s effective = 91% of the
// 6.29 TB/s measured mixed-traffic ceiling -> HBM-write roofline.

#define NN 1024

typedef float f32x4 __attribute__((ext_vector_type(4)));

__global__ __launch_bounds__(256) void KR_RPE_10582799417497_kernel(
    const float* __restrict__ kp,    // (8,5,2)
    const float* __restrict__ mesh,  // (1024,2)
    const float* __restrict__ W,     // (10,512)
    const int*   __restrict__ dm,    // (1024,1024)
    float* __restrict__ out)         // (8,8,1024,1024)
{
    const int bid  = blockIdx.x;
    const int g    = bid >> 10;       // plane group 0..15 (slow)
    const int n    = bid & (NN - 1);  // row 0..1023 (fast)
    const int t    = threadIdx.x;
    const int lane = t & 63;
    const int w    = t >> 6;          // wave 0..3
    const int bh   = g * 4 + w;       // this wave's output plane
    const int b    = bh >> 3, h = bh & 7;

    const int n0 = n >> 3;            // n_orig = h*128 + n0
    const int oo = (n & 7) * 64;      // o base
    const int k  = lane;              // this lane's table column

    // W column slice for k (coalesced 256 B per load)
    float Wv[10];
#pragma unroll
    for (int f = 0; f < 10; ++f) Wv[f] = W[f * 512 + oo + k];

    // one-register gather table: A[bh][k = lane]
    const int n_orig = h * 128 + n0;
    const float mx = mesh[n_orig * 2 + 0];
    const float my = mesh[n_orig * 2 + 1];
    float acc = 0.f;
#pragma unroll
    for (int p = 0; p < 5; ++p) {
        acc += (mx - kp[b * 10 + p * 2 + 0]) * Wv[p * 2 + 0]
             + (my - kp[b * 10 + p * 2 + 1]) * Wv[p * 2 + 1];
    }
    const int s = __float_as_int(acc);

    const int* dr = dm + (size_t)n * NN;              // shared by all 4 waves (L1)
    float* op = out + ((size_t)bh * NN + n) * NN;     // this wave's 4 KB row

#pragma unroll
    for (int it = 0; it < 4; ++it) {
        const int4 kk = *(const int4*)(dr + it * 256 + lane * 4);
        f32x4 v;
        v.x = __int_as_float(__builtin_amdgcn_ds_bpermute(kk.x * 4, s));
        v.y = __int_as_float(__builtin_amdgcn_ds_bpermute(kk.y * 4, s));
        v.z = __int_as_float(__builtin_amdgcn_ds_bpermute(kk.z * 4, s));
        v.w = __int_as_float(__builtin_amdgcn_ds_bpermute(kk.w * 4, s));
        __builtin_nontemporal_store(v, (f32x4*)(op + it * 256 + lane * 4));
    }
}

extern "C" void kernel_launch(void* const* d_in, const int* in_sizes, int n_in,
                              void* d_out, int out_size, void* d_ws, size_t ws_size,
                              hipStream_t stream) {
    const float* kp   = (const float*)d_in[0];
    const float* mesh = (const float*)d_in[1];
    const float* W    = (const float*)d_in[2];
    const int*   dm   = (const int*)d_in[3];
    float* out = (float*)d_out;

    KR_RPE_10582799417497_kernel<<<16 * NN, 256, 0, stream>>>(kp, mesh, W, dm, out);
}